// Round 4
// baseline (615.130 us; speedup 1.0000x reference)
//
#include <hip/hip_runtime.h>

// TATWindowAttention: B=16, n=100, L=64, C=256, H=8, Dh=32
// out = concat(x [B,n,L,C], attn [B,n,H,L,L]) fp32.
// v5: cross-tile software pipeline. One block per (4 windows, head):
//     3200 blocks x 256 threads (4 waves). Each block computes NT=4
//     consecutive bw tiles; loads for tile j+1 are issued between the two
//     barriers of tile j's staging phase and land during tile j's compute
//     (barriers are scheduling boundaries -> compiler can't sink the loads).
//     pos is per-(b,h), constant across the block's 4 tiles: loaded once.
// MFMA 16x16x32 bf16; split-bf16 (hi+lo) Q,K; bf16 P,V for PV (same numerics
// as v4: absmax must stay 0.03125).

typedef __attribute__((ext_vector_type(8))) short bf16x8;
typedef __attribute__((ext_vector_type(4))) float f32x4;

#define LOGIT_MAX_F 4.605170185988091f  // log(100)

__device__ __forceinline__ short f2bf(float f) {
    union { float f; unsigned u; } c; c.f = f;
    unsigned r = c.u + 0x7FFFu + ((c.u >> 16) & 1u);
    return (short)(r >> 16);
}
__device__ __forceinline__ float bf2f(short s) {
    union { unsigned u; float f; } c; c.u = ((unsigned)(unsigned short)s) << 16;
    return c.f;
}

// LDS layout (shorts): KHI[64*40] @0, KLO @2560, VT[32*72] @5120 (V^T),
// P[64*72] @7424.  Single-buffered: write-region [B1,B2], read-region
// [B2,next B1] are disjoint for K/VT; P is same-wave write->read.
#define KHI_OFF 0
#define KLO_OFF 2560
#define VT_OFF  5120
#define P_OFF   7424
#define SMEM_SHORTS 12032   // 24064 B -> 5 blocks/CU at launch_bounds(256,5)

__global__ __launch_bounds__(256, 5) void tat_attn_kernel(
    const float* __restrict__ Qg, const float* __restrict__ Kg,
    const float* __restrict__ Vg, const float* __restrict__ Pg,
    const float* __restrict__ LSg,
    float* __restrict__ Xout, float* __restrict__ Aout)
{
    constexpr int L = 64, C = 256, H = 8, NW = 100, NT = 4;
    __shared__ short smem[SMEM_SHORTS];

    const int blk  = blockIdx.x;
    const int h    = blk & 7;           // head pinned to XCD (blk%8 round-robin)
    const int grp  = blk >> 3;          // 0..399
    const int bw0  = grp * NT;          // first window of this block
    const int t    = threadIdx.x;
    const int wave = t >> 6;
    const int lane = t & 63;
    const int quad = lane >> 4;
    const int l15  = lane & 15;

    const int b = bw0 / NW;             // constant across NT tiles (NT | NW)
    const float* pb = Pg + (size_t)(b * H + h) * L * L;
    const float scale = __expf(fminf(LSg[h], LOGIT_MAX_F));

    // ---- position: same (b,h) for all NT tiles -> load once, keep in regs ----
    float posr[4][4];
    #pragma unroll
    for (int r = 0; r < 4; ++r) {
        const int cb = (16 * wave + quad * 4 + r) * L + l15;
        posr[0][r] = pb[cb];
        posr[1][r] = pb[cb + 16];
        posr[2][r] = pb[cb + 32];
        posr[3][r] = pb[cb + 48];
    }

    const int r8   = t >> 2;            // K staging row 0..63
    const int c8   = (t & 3) * 8;       // K staging col base
    const int qrow = 16 * wave + l15;

    const float* qp = Qg + (size_t)bw0 * L * C + h * 32;
    const float* kp = Kg + (size_t)bw0 * L * C + h * 32;
    const float* vp = Vg + (size_t)bw0 * L * C + h * 32;
    float* xp = Xout + (size_t)bw0 * L * C + h * 32;
    float* ap = Aout + ((size_t)bw0 * H + h) * L * L;

    // ---- prefetch tile 0 into regs ----
    float4 kr0 = *(const float4*)(kp + r8 * C + c8);
    float4 kr1 = *(const float4*)(kp + r8 * C + c8 + 4);
    float4 vr0 = *(const float4*)(vp + lane * C + wave * 8);
    float4 vr1 = *(const float4*)(vp + lane * C + wave * 8 + 4);
    float4 qr0 = *(const float4*)(qp + qrow * C + quad * 8);
    float4 qr1 = *(const float4*)(qp + qrow * C + quad * 8 + 4);

    #pragma unroll 1
    for (int j = 0; j < NT; ++j) {
        __syncthreads();   // B1: all waves done with tile j-1 compute -> LDS free

        // ---- stage K (split hi/lo bf16) from regs ----
        {
            const float ka[8] = {kr0.x,kr0.y,kr0.z,kr0.w,kr1.x,kr1.y,kr1.z,kr1.w};
            bf16x8 kh, kl;
            #pragma unroll
            for (int i = 0; i < 8; ++i) {
                const short hi = f2bf(ka[i]);
                kh[i] = hi;
                kl[i] = f2bf(ka[i] - bf2f(hi));
            }
            *(bf16x8*)(smem + KHI_OFF + r8 * 40 + c8) = kh;
            *(bf16x8*)(smem + KLO_OFF + r8 * 40 + c8) = kl;
        }
        // ---- stage V^T bf16: VT[d][k], wave w owns d = 8w..8w+7 ----
        {
            const float va[8] = {vr0.x,vr0.y,vr0.z,vr0.w,vr1.x,vr1.y,vr1.z,vr1.w};
            #pragma unroll
            for (int i = 0; i < 8; ++i)
                smem[VT_OFF + (wave * 8 + i) * 72 + lane] = f2bf(va[i]);
        }
        // ---- Q -> split bf16 fragment in regs ----
        bf16x8 qh, ql;
        {
            const float qa[8] = {qr0.x,qr0.y,qr0.z,qr0.w,qr1.x,qr1.y,qr1.z,qr1.w};
            #pragma unroll
            for (int i = 0; i < 8; ++i) {
                const short hi = f2bf(qa[i]);
                qh[i] = hi;
                ql[i] = f2bf(qa[i] - bf2f(hi));
            }
        }

        // ---- prefetch tile j+1 (in flight during this tile's compute) ----
        if (j + 1 < NT) {
            const float* kn = kp + (j + 1) * (L * C);
            const float* vn = vp + (j + 1) * (L * C);
            const float* qn = qp + (j + 1) * (L * C);
            kr0 = *(const float4*)(kn + r8 * C + c8);
            kr1 = *(const float4*)(kn + r8 * C + c8 + 4);
            vr0 = *(const float4*)(vn + lane * C + wave * 8);
            vr1 = *(const float4*)(vn + lane * C + wave * 8 + 4);
            qr0 = *(const float4*)(qn + qrow * C + quad * 8);
            qr1 = *(const float4*)(qn + qrow * C + quad * 8 + 4);
        }

        __syncthreads();   // B2: K/VT of tile j visible to all waves

        // ---- QK^T: wave w owns q-rows 16w..16w+15; 4 tiles of 16x16 ----
        f32x4 acc0 = {0,0,0,0}, acc1 = {0,0,0,0}, acc2 = {0,0,0,0}, acc3 = {0,0,0,0};
        #pragma unroll
        for (int t4 = 0; t4 < 4; ++t4) {
            const bf16x8 bkh = *(const bf16x8*)(smem + KHI_OFF + (16*t4 + l15)*40 + quad*8);
            const bf16x8 bkl = *(const bf16x8*)(smem + KLO_OFF + (16*t4 + l15)*40 + quad*8);
            f32x4 a = (t4==0)?acc0:(t4==1)?acc1:(t4==2)?acc2:acc3;
            a = __builtin_amdgcn_mfma_f32_16x16x32_bf16(qh, bkh, a, 0, 0, 0);
            a = __builtin_amdgcn_mfma_f32_16x16x32_bf16(qh, bkl, a, 0, 0, 0);
            a = __builtin_amdgcn_mfma_f32_16x16x32_bf16(ql, bkh, a, 0, 0, 0);
            if (t4==0) acc0 = a; else if (t4==1) acc1 = a; else if (t4==2) acc2 = a; else acc3 = a;
        }

        // ---- logits = acc*scale + pos ----
        float lg[4][4];
        #pragma unroll
        for (int r = 0; r < 4; ++r) {
            lg[0][r] = fmaf(acc0[r], scale, posr[0][r]);
            lg[1][r] = fmaf(acc1[r], scale, posr[1][r]);
            lg[2][r] = fmaf(acc2[r], scale, posr[2][r]);
            lg[3][r] = fmaf(acc3[r], scale, posr[3][r]);
        }

        // ---- softmax per row ----
        float p[4][4];
        #pragma unroll
        for (int r = 0; r < 4; ++r) {
            float m = fmaxf(fmaxf(lg[0][r], lg[1][r]), fmaxf(lg[2][r], lg[3][r]));
            #pragma unroll
            for (int off = 8; off > 0; off >>= 1) m = fmaxf(m, __shfl_xor(m, off));
            const float e0 = __expf(lg[0][r] - m);
            const float e1 = __expf(lg[1][r] - m);
            const float e2 = __expf(lg[2][r] - m);
            const float e3 = __expf(lg[3][r] - m);
            float s = (e0 + e1) + (e2 + e3);
            #pragma unroll
            for (int off = 8; off > 0; off >>= 1) s += __shfl_xor(s, off);
            const float inv = 1.0f / s;
            p[0][r] = e0 * inv; p[1][r] = e1 * inv; p[2][r] = e2 * inv; p[3][r] = e3 * inv;
        }

        float* xb = xp + j * (L * C);
        float* ab = ap + (size_t)j * H * L * L;

        // ---- attn out (fp32 exact) + P -> LDS (bf16; own-wave rows) ----
        #pragma unroll
        for (int r = 0; r < 4; ++r) {
            const int row = 16 * wave + quad * 4 + r;
            #pragma unroll
            for (int t4 = 0; t4 < 4; ++t4) {
                const int col = 16 * t4 + l15;
                ab[row * L + col] = p[t4][r];
                smem[P_OFF + row * 72 + col] = f2bf(p[t4][r]);
            }
        }

        // ---- PV: O[16x32] per wave = P[16x64] x V[64x32] ----
        f32x4 o0 = {0,0,0,0}, o1 = {0,0,0,0};
        #pragma unroll
        for (int hh = 0; hh < 2; ++hh) {
            const bf16x8 app = *(const bf16x8*)(smem + P_OFF + (16*wave + l15)*72 + hh*32 + quad*8);
            const bf16x8 bv0 = *(const bf16x8*)(smem + VT_OFF + l15*72        + hh*32 + quad*8);
            const bf16x8 bv1 = *(const bf16x8*)(smem + VT_OFF + (l15+16)*72   + hh*32 + quad*8);
            o0 = __builtin_amdgcn_mfma_f32_16x16x32_bf16(app, bv0, o0, 0, 0, 0);
            o1 = __builtin_amdgcn_mfma_f32_16x16x32_bf16(app, bv1, o1, 0, 0, 0);
        }

        #pragma unroll
        for (int r = 0; r < 4; ++r) {
            const int row = 16 * wave + quad * 4 + r;
            xb[row * C + l15]      = o0[r];
            xb[row * C + 16 + l15] = o1[r];
        }
    }
}

extern "C" void kernel_launch(void* const* d_in, const int* in_sizes, int n_in,
                              void* d_out, int out_size, void* d_ws, size_t ws_size,
                              hipStream_t stream) {
    const float* q   = (const float*)d_in[0];
    const float* k   = (const float*)d_in[1];
    const float* v   = (const float*)d_in[2];
    const float* pos = (const float*)d_in[3];
    const float* ls  = (const float*)d_in[4];
    float* out = (float*)d_out;

    constexpr int B = 16, NW = 100, L = 64, C = 256, H = 8, NT = 4;
    float* x_out = out;
    float* a_out = out + (size_t)B * NW * L * C;

    const int blocks = B * NW * H / NT;   // 3200
    tat_attn_kernel<<<blocks, 256, 0, stream>>>(q, k, v, pos, ls, x_out, a_out);
}